// Round 3
// baseline (668.569 us; speedup 1.0000x reference)
//
#include <hip/hip_runtime.h>
#include <math.h>

typedef __bf16 bf16x8 __attribute__((ext_vector_type(8)));
typedef __bf16 bf16x4 __attribute__((ext_vector_type(4)));
typedef float  floatx4 __attribute__((ext_vector_type(4)));

#define AS1(p) ((__attribute__((address_space(1))) void*)(p))
#define AS3(p) ((__attribute__((address_space(3))) void*)(p))

#define MASKV (-1.0e30f)

// ---------------------------------------------------------------------------
// fp32 -> bf16 conversion, 4 elems/thread, fully coalesced.
// ---------------------------------------------------------------------------
__global__ __launch_bounds__(256)
void cvt_kernel(const float* __restrict__ in, __bf16* __restrict__ out)
{
    const int i = (blockIdx.x * 256 + threadIdx.x) * 4;
    const floatx4 v = *(const floatx4*)(in + i);
    bf16x4 o;
    o[0] = (__bf16)v[0]; o[1] = (__bf16)v[1];
    o[2] = (__bf16)v[2]; o[3] = (__bf16)v[3];
    *(bf16x4*)(out + i) = o;
}

// ---------------------------------------------------------------------------
// C[M][N] = A[M][K] * BT[N][K]^T   (bf16 in, OT out, fp32 accum)
// 128x128 tile per 256-thread block, BK=32, global_load_lds width-16 staging.
// Layouts (learn_hip verified): A-frag A[m=lane&15][k=quad*8+j],
// B-frag BT[n=lane&15][k=quad*8+j], C/D col=lane&15 row=quad*4+reg.
// ---------------------------------------------------------------------------
template <typename OT>
__global__ __launch_bounds__(256)
void gemm_bt_kernel(const __bf16* __restrict__ A, const __bf16* __restrict__ BT,
                    OT* __restrict__ C, int M, int N, int K)
{
    __shared__ __align__(16) __bf16 As[128 * 32];
    __shared__ __align__(16) __bf16 Bs[128 * 32];

    const int tid  = threadIdx.x;
    const int wave = tid >> 6;
    const int lane = tid & 63;
    const int quad = lane >> 4;
    const int l16  = lane & 15;

    const long m0 = (long)blockIdx.y * 128;
    const long n0 = (long)blockIdx.x * 128;
    const int  wm = (wave >> 1) * 64;
    const int  wn = (wave & 1) * 64;

    floatx4 acc[4][4] = {};

    for (int k0 = 0; k0 < K; k0 += 32) {
        // stage 128x32 A-tile and B-tile: chunk c (16B) -> row c>>2, k-sub c&3
#pragma unroll
        for (int t = 0; t < 2; ++t) {
            const int c   = (t * 4 + wave) * 64 + lane;
            const int row = c >> 2;
            const int kc  = (c & 3) * 8;
            const __bf16* ga = A  + (m0 + row) * (long)K + k0 + kc;
            const __bf16* gb = BT + (n0 + row) * (long)K + k0 + kc;
            // LDS dest is wave-uniform base + lane*16
            __builtin_amdgcn_global_load_lds(AS1(ga), AS3(As + (t * 4 + wave) * 512), 16, 0, 0);
            __builtin_amdgcn_global_load_lds(AS1(gb), AS3(Bs + (t * 4 + wave) * 512), 16, 0, 0);
        }
        asm volatile("s_waitcnt vmcnt(0)" ::: "memory");
        __syncthreads();

        bf16x8 af[4], bfq[4];
#pragma unroll
        for (int mt = 0; mt < 4; ++mt)
            af[mt] = *(const bf16x8*)(As + (wm + mt * 16 + l16) * 32 + quad * 8);
#pragma unroll
        for (int nt = 0; nt < 4; ++nt)
            bfq[nt] = *(const bf16x8*)(Bs + (wn + nt * 16 + l16) * 32 + quad * 8);

#pragma unroll
        for (int mt = 0; mt < 4; ++mt)
#pragma unroll
            for (int nt = 0; nt < 4; ++nt)
                acc[mt][nt] = __builtin_amdgcn_mfma_f32_16x16x32_bf16(
                    af[mt], bfq[nt], acc[mt][nt], 0, 0, 0);
        __syncthreads();
    }

#pragma unroll
    for (int mt = 0; mt < 4; ++mt)
#pragma unroll
        for (int nt = 0; nt < 4; ++nt) {
            const long row = m0 + wm + mt * 16 + quad * 4;
            const long col = n0 + wn + nt * 16 + l16;
#pragma unroll
            for (int r = 0; r < 4; ++r)
                C[(row + r) * (long)N + col] = (OT)acc[mt][nt][r];
        }
}

// ---------------------------------------------------------------------------
// RoPE + layout transform.
// QKV[8192][3072] -> Qr[bh][s][64], Kr[bh][s][64] (roped), Vt[bh][64][2048].
// grid = (64 bh, 8 s-tiles), block = 256 (thread = one s).
// ---------------------------------------------------------------------------
__global__ __launch_bounds__(256)
void rope_kernel(const __bf16* __restrict__ QKV,
                 __bf16* __restrict__ Qr, __bf16* __restrict__ Kr,
                 __bf16* __restrict__ Vt)
{
    const int bh = blockIdx.x;
    const int b  = bh >> 4, h = bh & 15;
    const int s  = blockIdx.y * 256 + threadIdx.x;

    const __bf16* base = QKV + ((size_t)(b * 2048 + s)) * 3072 + h * 64;

    float q[64], k[64];
#pragma unroll
    for (int d = 0; d < 64; ++d) {
        q[d] = (float)base[d];
        k[d] = (float)base[1024 + d];
    }

    __attribute__((aligned(16))) __bf16 qo[64];
    __attribute__((aligned(16))) __bf16 ko[64];

#pragma unroll
    for (int d = 0; d < 32; ++d) {
        // inv_freq = 10000^(-d/32) = 2^(-d*log2(10000)/32)
        const float f   = exp2f(-(float)d * 0.4152410118609203f);
        const float ang = (float)s * f;
        float sn, cs;
        sincosf(ang, &sn, &cs);
        qo[d]      = (__bf16)(q[d] * cs - q[d + 32] * sn);
        qo[d + 32] = (__bf16)(q[d + 32] * cs + q[d] * sn);
        ko[d]      = (__bf16)(k[d] * cs - k[d + 32] * sn);
        ko[d + 32] = (__bf16)(k[d + 32] * cs + k[d] * sn);
    }

    __bf16* qdst = Qr + ((size_t)bh * 2048 + s) * 64;
    __bf16* kdst = Kr + ((size_t)bh * 2048 + s) * 64;
#pragma unroll
    for (int i = 0; i < 8; ++i) {
        *(bf16x8*)(qdst + i * 8) = ((const bf16x8*)qo)[i];
        *(bf16x8*)(kdst + i * 8) = ((const bf16x8*)ko)[i];
    }
    // V transpose: coalesced across lanes (consecutive s) per d
#pragma unroll
    for (int d = 0; d < 64; ++d)
        Vt[((size_t)bh * 64 + d) * 2048 + s] = base[2048 + d];
}

// ---------------------------------------------------------------------------
// Causal flash attention. grid = (32 q-tiles of 64, 64 bh), block = 256.
// Each wave owns 16 q-rows; k-tiles of 32; online softmax fp32 with finite
// sentinels (no inf anywhere: exp args always <= 0).
// ---------------------------------------------------------------------------
__global__ __launch_bounds__(256)
void attn_kernel(const __bf16* __restrict__ Qr, const __bf16* __restrict__ Kr,
                 const __bf16* __restrict__ Vt, __bf16* __restrict__ ctx)
{
    __shared__ __align__(16) __bf16 plds[4][16 * 40];   // wave-private P staging

    const int bh   = blockIdx.y;
    const int b    = bh >> 4, h = bh & 15;
    const int wave = threadIdx.x >> 6;
    const int lane = threadIdx.x & 63;
    const int quad = lane >> 4, l16 = lane & 15;
    const int q0   = blockIdx.x * 64 + wave * 16;

    const __bf16* Qb = Qr + (size_t)bh * 2048 * 64;
    const __bf16* Kb = Kr + (size_t)bh * 2048 * 64;
    const __bf16* Vb = Vt + (size_t)bh * 64 * 2048;

    bf16x8 aq[2];
#pragma unroll
    for (int t = 0; t < 2; ++t)
        aq[t] = *(const bf16x8*)(Qb + (q0 + l16) * 64 + t * 32 + quad * 8);

    floatx4 o[4] = {};
    float mst[4], lst[4];
#pragma unroll
    for (int r = 0; r < 4; ++r) { mst[r] = MASKV; lst[r] = 0.f; }

    __bf16* Pw = &plds[wave][0];

    const int kend = q0 + 16;   // keys 0 .. q0+15 inclusive
    for (int kt = 0; kt < kend; kt += 32) {
        floatx4 s0 = {}, s1 = {};
#pragma unroll
        for (int t = 0; t < 2; ++t) {
            bf16x8 bk0 = *(const bf16x8*)(Kb + (kt      + l16) * 64 + t * 32 + quad * 8);
            bf16x8 bk1 = *(const bf16x8*)(Kb + (kt + 16 + l16) * 64 + t * 32 + quad * 8);
            s0 = __builtin_amdgcn_mfma_f32_16x16x32_bf16(aq[t], bk0, s0, 0, 0, 0);
            s1 = __builtin_amdgcn_mfma_f32_16x16x32_bf16(aq[t], bk1, s1, 0, 0, 0);
        }

        float alpha[4];
#pragma unroll
        for (int r = 0; r < 4; ++r) {
            const int qrow = q0 + quad * 4 + r;
            float v0 = (kt      + l16 > qrow) ? MASKV : s0[r] * 0.125f;
            float v1 = (kt + 16 + l16 > qrow) ? MASKV : s1[r] * 0.125f;

            float mx = fmaxf(v0, v1);
#pragma unroll
            for (int off = 1; off < 16; off <<= 1)
                mx = fmaxf(mx, __shfl_xor(mx, off, 64));
            const float mnew = fmaxf(mst[r], mx);
            alpha[r] = __expf(mst[r] - mnew);   // first iter: exp(-1e30) = 0
            mst[r] = mnew;

            const float p0 = __expf(v0 - mnew);  // masked: exp(<= -1e30+..) = 0
            const float p1 = __expf(v1 - mnew);
            float ps = p0 + p1;
#pragma unroll
            for (int off = 1; off < 16; off <<= 1)
                ps += __shfl_xor(ps, off, 64);
            lst[r] = lst[r] * alpha[r] + ps;

            Pw[(quad * 4 + r) * 40 + l16]      = (__bf16)p0;
            Pw[(quad * 4 + r) * 40 + 16 + l16] = (__bf16)p1;
        }

#pragma unroll
        for (int nt = 0; nt < 4; ++nt)
#pragma unroll
            for (int r = 0; r < 4; ++r)
                o[nt][r] *= alpha[r];

        asm volatile("s_waitcnt lgkmcnt(0)" ::: "memory");  // P writes visible wave-wide
        bf16x8 ap = *(const bf16x8*)(Pw + l16 * 40 + quad * 8);

#pragma unroll
        for (int nt = 0; nt < 4; ++nt) {
            bf16x8 bv = *(const bf16x8*)(Vb + (nt * 16 + l16) * 2048 + kt + quad * 8);
            o[nt] = __builtin_amdgcn_mfma_f32_16x16x32_bf16(ap, bv, o[nt], 0, 0, 0);
        }
    }

#pragma unroll
    for (int nt = 0; nt < 4; ++nt)
#pragma unroll
        for (int r = 0; r < 4; ++r) {
            const int s = q0 + quad * 4 + r;
            const float inv_l = 1.0f / fmaxf(lst[r], 1e-20f);
            ctx[((size_t)(b * 2048 + s)) * 1024 + h * 64 + nt * 16 + l16] =
                (__bf16)(o[nt][r] * inv_l);
        }
}

// ---------------------------------------------------------------------------
// Workspace layout (96 MiB total, same footprint as prior rounds):
//   [ 0M..48M)  QKV bf16 (dead after rope)  -> ctx bf16 [0..16M), wob [16M..18M)
//   [48M..64M)  xb bf16  (dead after GEMM1) -> Qr bf16
//   [64M..80M)  qkvb bf16 [64..70M) (dead after GEMM1) -> Kr bf16
//   [80M..96M)  Vt bf16
// ---------------------------------------------------------------------------
extern "C" void kernel_launch(void* const* d_in, const int* in_sizes, int n_in,
                              void* d_out, int out_size, void* d_ws, size_t ws_size,
                              hipStream_t stream)
{
    const float* x   = (const float*)d_in[0];   // [4,2048,1024] fp32
    const float* qkv = (const float*)d_in[1];   // [3072,1024]   fp32 (N x K)
    const float* wo  = (const float*)d_in[2];   // [1024,1024]   fp32 (N x K)
    float* out = (float*)d_out;                 // [8192,1024]   fp32

    char* ws = (char*)d_ws;
    const size_t MB = 1024 * 1024;
    __bf16* QKV  = (__bf16*)(ws);
    __bf16* ctx  = (__bf16*)(ws);               // overlaps dead QKV
    __bf16* wob  = (__bf16*)(ws + 16 * MB);     // overlaps dead QKV
    __bf16* Qr   = (__bf16*)(ws + 48 * MB);
    __bf16* xb   = (__bf16*)(ws + 48 * MB);     // dead before Qr written
    __bf16* Kr   = (__bf16*)(ws + 64 * MB);
    __bf16* qkvb = (__bf16*)(ws + 64 * MB);     // dead before Kr written
    __bf16* Vt   = (__bf16*)(ws + 80 * MB);

    // 0) fp32 -> bf16 input conversion
    cvt_kernel<<<8192, 256, 0, stream>>>(x,   xb);    // 8388608 elems
    cvt_kernel<<<3072, 256, 0, stream>>>(qkv, qkvb);  // 3145728 elems
    // 1) QKV projection (bf16 MFMA, fp32 accum)
    gemm_bt_kernel<__bf16><<<dim3(24, 64), 256, 0, stream>>>(xb, qkvb, QKV, 8192, 3072, 1024);
    // 2) RoPE + head-major layout + V transpose  (QKV, xb, qkvb die here)
    rope_kernel<<<dim3(64, 8), 256, 0, stream>>>(QKV, Qr, Kr, Vt);
    // 2b) wo conversion into dead QKV region
    cvt_kernel<<<1024, 256, 0, stream>>>(wo, wob);    // 1048576 elems
    // 3) causal flash attention -> ctx (bf16)
    attn_kernel<<<dim3(32, 64), 256, 0, stream>>>(Qr, Kr, Vt, ctx);
    // 4) output projection -> fp32 out
    gemm_bt_kernel<float><<<dim3(8, 64), 256, 0, stream>>>(ctx, wob, out, 8192, 1024, 1024);
}

// Round 4
// 452.533 us; speedup vs baseline: 1.4774x; 1.4774x over previous
//
#include <hip/hip_runtime.h>
#include <math.h>

typedef __bf16 bf16x8 __attribute__((ext_vector_type(8)));
typedef __bf16 bf16x4 __attribute__((ext_vector_type(4)));
typedef float  floatx4 __attribute__((ext_vector_type(4)));

#define AS1(p) ((__attribute__((address_space(1))) void*)(p))
#define AS3(p) ((__attribute__((address_space(3))) void*)(p))

#define MASKV (-1.0e30f)

// ---------------------------------------------------------------------------
// fp32 -> bf16 conversion, 4 elems/thread, fully coalesced.
// ---------------------------------------------------------------------------
__global__ __launch_bounds__(256)
void cvt_kernel(const float* __restrict__ in, __bf16* __restrict__ out)
{
    const int i = (blockIdx.x * 256 + threadIdx.x) * 4;
    const floatx4 v = *(const floatx4*)(in + i);
    bf16x4 o;
    o[0] = (__bf16)v[0]; o[1] = (__bf16)v[1];
    o[2] = (__bf16)v[2]; o[3] = (__bf16)v[3];
    *(bf16x4*)(out + i) = o;
}

// ---------------------------------------------------------------------------
// C[M][N] = A[M][K] * BT[N][K]^T   (bf16 in, OT out, fp32 accum)
// 128x128 tile per 256-thread block, BK=32, global_load_lds width-16 staging.
// ---------------------------------------------------------------------------
template <typename OT>
__global__ __launch_bounds__(256)
void gemm_bt_kernel(const __bf16* __restrict__ A, const __bf16* __restrict__ BT,
                    OT* __restrict__ C, int M, int N, int K)
{
    __shared__ __align__(16) __bf16 As[128 * 32];
    __shared__ __align__(16) __bf16 Bs[128 * 32];

    const int tid  = threadIdx.x;
    const int wave = tid >> 6;
    const int lane = tid & 63;
    const int quad = lane >> 4;
    const int l16  = lane & 15;

    const long m0 = (long)blockIdx.y * 128;
    const long n0 = (long)blockIdx.x * 128;
    const int  wm = (wave >> 1) * 64;
    const int  wn = (wave & 1) * 64;

    floatx4 acc[4][4] = {};

    for (int k0 = 0; k0 < K; k0 += 32) {
#pragma unroll
        for (int t = 0; t < 2; ++t) {
            const int c   = (t * 4 + wave) * 64 + lane;
            const int row = c >> 2;
            const int kc  = (c & 3) * 8;
            const __bf16* ga = A  + (m0 + row) * (long)K + k0 + kc;
            const __bf16* gb = BT + (n0 + row) * (long)K + k0 + kc;
            __builtin_amdgcn_global_load_lds(AS1(ga), AS3(As + (t * 4 + wave) * 512), 16, 0, 0);
            __builtin_amdgcn_global_load_lds(AS1(gb), AS3(Bs + (t * 4 + wave) * 512), 16, 0, 0);
        }
        asm volatile("s_waitcnt vmcnt(0)" ::: "memory");
        __syncthreads();

        bf16x8 af[4], bfq[4];
#pragma unroll
        for (int mt = 0; mt < 4; ++mt)
            af[mt] = *(const bf16x8*)(As + (wm + mt * 16 + l16) * 32 + quad * 8);
#pragma unroll
        for (int nt = 0; nt < 4; ++nt)
            bfq[nt] = *(const bf16x8*)(Bs + (wn + nt * 16 + l16) * 32 + quad * 8);

#pragma unroll
        for (int mt = 0; mt < 4; ++mt)
#pragma unroll
            for (int nt = 0; nt < 4; ++nt)
                acc[mt][nt] = __builtin_amdgcn_mfma_f32_16x16x32_bf16(
                    af[mt], bfq[nt], acc[mt][nt], 0, 0, 0);
        __syncthreads();
    }

#pragma unroll
    for (int mt = 0; mt < 4; ++mt)
#pragma unroll
        for (int nt = 0; nt < 4; ++nt) {
            const long row = m0 + wm + mt * 16 + quad * 4;
            const long col = n0 + wn + nt * 16 + l16;
#pragma unroll
            for (int r = 0; r < 4; ++r)
                C[(row + r) * (long)N + col] = (OT)acc[mt][nt][r];
        }
}

// ---------------------------------------------------------------------------
// RoPE + layout transform.
// QKV[8192][3072] -> Qr[bh][s][64], Kr[bh][s][64] (roped), Vt[bh][64][2048].
// ---------------------------------------------------------------------------
__global__ __launch_bounds__(256)
void rope_kernel(const __bf16* __restrict__ QKV,
                 __bf16* __restrict__ Qr, __bf16* __restrict__ Kr,
                 __bf16* __restrict__ Vt)
{
    const int bh = blockIdx.x;
    const int b  = bh >> 4, h = bh & 15;
    const int s  = blockIdx.y * 256 + threadIdx.x;

    const __bf16* base = QKV + ((size_t)(b * 2048 + s)) * 3072 + h * 64;

    float q[64], k[64];
#pragma unroll
    for (int d = 0; d < 64; ++d) {
        q[d] = (float)base[d];
        k[d] = (float)base[1024 + d];
    }

    __attribute__((aligned(16))) __bf16 qo[64];
    __attribute__((aligned(16))) __bf16 ko[64];

#pragma unroll
    for (int d = 0; d < 32; ++d) {
        const float f   = exp2f(-(float)d * 0.4152410118609203f);
        const float ang = (float)s * f;
        float sn, cs;
        sincosf(ang, &sn, &cs);
        qo[d]      = (__bf16)(q[d] * cs - q[d + 32] * sn);
        qo[d + 32] = (__bf16)(q[d + 32] * cs + q[d] * sn);
        ko[d]      = (__bf16)(k[d] * cs - k[d + 32] * sn);
        ko[d + 32] = (__bf16)(k[d + 32] * cs + k[d] * sn);
    }

    __bf16* qdst = Qr + ((size_t)bh * 2048 + s) * 64;
    __bf16* kdst = Kr + ((size_t)bh * 2048 + s) * 64;
#pragma unroll
    for (int i = 0; i < 8; ++i) {
        *(bf16x8*)(qdst + i * 8) = ((const bf16x8*)qo)[i];
        *(bf16x8*)(kdst + i * 8) = ((const bf16x8*)ko)[i];
    }
#pragma unroll
    for (int d = 0; d < 64; ++d)
        Vt[((size_t)bh * 64 + d) * 2048 + s] = base[2048 + d];
}

// ---------------------------------------------------------------------------
// Causal flash attention v2. grid = (16 paired q-tiles, 64 bh), block = 256.
// Each block processes q-tiles {qb, 31-qb} (uniform work). Each wave owns
// 16 q-rows. S is computed TRANSPOSED (S^T = K*Q^T) so a softmax row lives
// in 8 in-lane regs + 2 cross-quad shfls (vs 32 shfl-ops before).
// Softmax state m,l: one scalar per lane (lane&15 = q-row).
// ---------------------------------------------------------------------------
__global__ __launch_bounds__(256, 4)
void attn_kernel(const __bf16* __restrict__ Qr, const __bf16* __restrict__ Kr,
                 const __bf16* __restrict__ Vt, __bf16* __restrict__ ctx)
{
    __shared__ __align__(16) __bf16 plds[4][16 * 40];   // wave-private P staging

    const int bh   = blockIdx.y;
    const int b    = bh >> 4, h = bh & 15;
    const int wave = threadIdx.x >> 6;
    const int lane = threadIdx.x & 63;
    const int quad = lane >> 4, l16 = lane & 15;

    const __bf16* Qb = Qr + (size_t)bh * 2048 * 64;
    const __bf16* Kb = Kr + (size_t)bh * 2048 * 64;
    const __bf16* Vb = Vt + (size_t)bh * 64 * 2048;
    __bf16* Pw = &plds[wave][0];

    for (int pass = 0; pass < 2; ++pass) {
        const int qb = pass ? (31 - (int)blockIdx.x) : (int)blockIdx.x;
        const int q0 = qb * 64 + wave * 16;
        const int qa = q0 + l16;            // this lane's q-row (softmax domain)

        bf16x8 bq[2];
#pragma unroll
        for (int t = 0; t < 2; ++t)
            bq[t] = *(const bf16x8*)(Qb + (q0 + l16) * 64 + t * 32 + quad * 8);

        floatx4 o[4] = {};
        float m = MASKV, l = 0.f;

        const int kend = q0 + 16;           // keys 0 .. q0+15 inclusive

        // prefetch first K tile (A-frags: rows = keys)
        bf16x8 ka0[2], ka1[2];
#pragma unroll
        for (int t = 0; t < 2; ++t) {
            ka0[t] = *(const bf16x8*)(Kb + (l16)      * 64 + t * 32 + quad * 8);
            ka1[t] = *(const bf16x8*)(Kb + (16 + l16) * 64 + t * 32 + quad * 8);
        }

        for (int kt = 0; kt < kend; kt += 32) {
            // S^T tiles: D[key=quad*4+r][q=l16]
            floatx4 s0 = {}, s1 = {};
            s0 = __builtin_amdgcn_mfma_f32_16x16x32_bf16(ka0[0], bq[0], s0, 0, 0, 0);
            s0 = __builtin_amdgcn_mfma_f32_16x16x32_bf16(ka0[1], bq[1], s0, 0, 0, 0);
            s1 = __builtin_amdgcn_mfma_f32_16x16x32_bf16(ka1[0], bq[0], s1, 0, 0, 0);
            s1 = __builtin_amdgcn_mfma_f32_16x16x32_bf16(ka1[1], bq[1], s1, 0, 0, 0);

            // prefetch V for this tile (independent of softmax)
            bf16x8 bv[4];
#pragma unroll
            for (int nt = 0; nt < 4; ++nt)
                bv[nt] = *(const bf16x8*)(Vb + (nt * 16 + l16) * 2048 + kt + quad * 8);

            // prefetch next K tile
            if (kt + 32 < kend) {
#pragma unroll
                for (int t = 0; t < 2; ++t) {
                    ka0[t] = *(const bf16x8*)(Kb + (kt + 32 + l16) * 64 + t * 32 + quad * 8);
                    ka1[t] = *(const bf16x8*)(Kb + (kt + 48 + l16) * 64 + t * 32 + quad * 8);
                }
            }

            // mask + scale (key index = kt + quad*4 + r / +16)
            float v0[4], v1[4];
#pragma unroll
            for (int r = 0; r < 4; ++r) {
                v0[r] = (kt + quad * 4 + r      > qa) ? MASKV : s0[r] * 0.125f;
                v1[r] = (kt + 16 + quad * 4 + r > qa) ? MASKV : s1[r] * 0.125f;
            }

            // row max: 8 in-lane + 2 cross-quad shfls
            float mx = fmaxf(fmaxf(fmaxf(v0[0], v0[1]), fmaxf(v0[2], v0[3])),
                             fmaxf(fmaxf(v1[0], v1[1]), fmaxf(v1[2], v1[3])));
            mx = fmaxf(mx, __shfl_xor(mx, 16, 64));
            mx = fmaxf(mx, __shfl_xor(mx, 32, 64));
            const float mnew = fmaxf(m, mx);
            const float alpha = __expf(m - mnew);   // first iter: exp(-1e30)=0
            m = mnew;

            float p0[4], p1[4], ps = 0.f;
#pragma unroll
            for (int r = 0; r < 4; ++r) {
                p0[r] = __expf(v0[r] - mnew);
                p1[r] = __expf(v1[r] - mnew);
                ps += p0[r] + p1[r];
            }
            ps += __shfl_xor(ps, 16, 64);
            ps += __shfl_xor(ps, 32, 64);
            l = l * alpha + ps;

            // store P in [q][key] rows: row l16, cols quad*4+r (+16)
            bf16x4 w0, w1;
#pragma unroll
            for (int r = 0; r < 4; ++r) { w0[r] = (__bf16)p0[r]; w1[r] = (__bf16)p1[r]; }
            *(bf16x4*)(Pw + l16 * 40 + quad * 4)      = w0;
            *(bf16x4*)(Pw + l16 * 40 + 16 + quad * 4) = w1;

            // rescale O rows (row q=quad*4+r; alpha lives at lane l16=quad*4+r)
            float ar[4];
#pragma unroll
            for (int r = 0; r < 4; ++r)
                ar[r] = __shfl(alpha, quad * 4 + r, 64);
#pragma unroll
            for (int nt = 0; nt < 4; ++nt)
#pragma unroll
                for (int r = 0; r < 4; ++r)
                    o[nt][r] *= ar[r];

            asm volatile("s_waitcnt lgkmcnt(0)" ::: "memory");
            bf16x8 ap = *(const bf16x8*)(Pw + l16 * 40 + quad * 8);  // A[q][key]

#pragma unroll
            for (int nt = 0; nt < 4; ++nt)
                o[nt] = __builtin_amdgcn_mfma_f32_16x16x32_bf16(ap, bv[nt], o[nt], 0, 0, 0);
        }

        // epilogue: O row q=quad*4+r needs l from lane l16=quad*4+r
        float lr[4];
#pragma unroll
        for (int r = 0; r < 4; ++r)
            lr[r] = __shfl(l, quad * 4 + r, 64);
#pragma unroll
        for (int nt = 0; nt < 4; ++nt)
#pragma unroll
            for (int r = 0; r < 4; ++r) {
                const int s = q0 + quad * 4 + r;
                const float inv_l = 1.0f / fmaxf(lr[r], 1e-20f);
                ctx[((size_t)(b * 2048 + s)) * 1024 + h * 64 + nt * 16 + l16] =
                    (__bf16)(o[nt][r] * inv_l);
            }
    }
}

// ---------------------------------------------------------------------------
// Workspace layout (96 MiB):
//   [ 0M..48M)  QKV bf16 (dead after rope) -> ctx [0..16M), wob [16M..18M)
//   [48M..64M)  xb bf16 (dead after GEMM1) -> Qr
//   [64M..80M)  qkvb bf16 (dead after GEMM1) -> Kr
//   [80M..96M)  Vt bf16
// ---------------------------------------------------------------------------
extern "C" void kernel_launch(void* const* d_in, const int* in_sizes, int n_in,
                              void* d_out, int out_size, void* d_ws, size_t ws_size,
                              hipStream_t stream)
{
    const float* x   = (const float*)d_in[0];   // [4,2048,1024] fp32
    const float* qkv = (const float*)d_in[1];   // [3072,1024]   fp32 (N x K)
    const float* wo  = (const float*)d_in[2];   // [1024,1024]   fp32 (N x K)
    float* out = (float*)d_out;                 // [8192,1024]   fp32

    char* ws = (char*)d_ws;
    const size_t MB = 1024 * 1024;
    __bf16* QKV  = (__bf16*)(ws);
    __bf16* ctx  = (__bf16*)(ws);               // overlaps dead QKV
    __bf16* wob  = (__bf16*)(ws + 16 * MB);     // overlaps dead QKV
    __bf16* Qr   = (__bf16*)(ws + 48 * MB);
    __bf16* xb   = (__bf16*)(ws + 48 * MB);     // dead before Qr written
    __bf16* Kr   = (__bf16*)(ws + 64 * MB);
    __bf16* qkvb = (__bf16*)(ws + 64 * MB);     // dead before Kr written
    __bf16* Vt   = (__bf16*)(ws + 80 * MB);

    cvt_kernel<<<8192, 256, 0, stream>>>(x,   xb);
    cvt_kernel<<<3072, 256, 0, stream>>>(qkv, qkvb);
    gemm_bt_kernel<__bf16><<<dim3(24, 64), 256, 0, stream>>>(xb, qkvb, QKV, 8192, 3072, 1024);
    rope_kernel<<<dim3(64, 8), 256, 0, stream>>>(QKV, Qr, Kr, Vt);
    cvt_kernel<<<1024, 256, 0, stream>>>(wo, wob);
    attn_kernel<<<dim3(16, 64), 256, 0, stream>>>(Qr, Kr, Vt, ctx);
    gemm_bt_kernel<float><<<dim3(8, 64), 256, 0, stream>>>(ctx, wob, out, 8192, 1024, 1024);
}